// Round 9
// baseline (225.316 us; speedup 1.0000x reference)
//
#include <hip/hip_runtime.h>

// B=8, C=256, H=W=32 -> S=1024; NH=8, DK=256; qkv dim 6144.
#define NH    8
#define DK    256
#define SS    1024
// q is pre-scaled by SCALE*log2(e) in k1 so softmax runs in exp2 domain.
#define QSCALE 0.09016844136947155f   // (1/16) * 1.4426950408889634
#define TSH   8192                    // shorts per 16 KB tile (32 rows x 256 k)

using frag8  = __attribute__((ext_vector_type(8))) short;   // 8 bf16 (4 VGPRs)
using f32x16 = __attribute__((ext_vector_type(16))) float;  // 32x32 MFMA acc

__device__ __forceinline__ unsigned short f2bf(float f) {
    unsigned int u = __float_as_uint(f);
    return (unsigned short)((u + 0x7FFFu + ((u >> 16) & 1u)) >> 16);   // RNE
}
__device__ __forceinline__ unsigned int pk2bf(float lo, float hi) {
    unsigned int ul = __float_as_uint(lo), uh = __float_as_uint(hi);
    ul += 0x7FFFu + ((ul >> 16) & 1u);
    uh += 0x7FFFu + ((uh >> 16) & 1u);
    return (ul >> 16) | (uh & 0xFFFF0000u);
}

// async global->LDS, 16B/lane; LDS dest = wave-uniform base + lane*16.
__device__ __forceinline__ void load_lds16(const void* g, void* l) {
    __builtin_amdgcn_global_load_lds(
        (const __attribute__((address_space(1))) unsigned int*)g,
        (__attribute__((address_space(3))) unsigned int*)l, 16, 0, 0);
}

// T32 format: a panel = 32 rows x K columns; cell(row r, kchunk c) = 8 shorts
// at (c*32 + r)*8.  Conflict-free MFMA frag reads: 64 lanes -> 64 consecutive
// 16B cells.  q/k global = T32 panels of 8192 shorts (K=256), rows=tokens,
// cols=d.  v = key-permuted (unchanged from r7).  O (over qb) = q/k format.

// ---------------------------------------------------------------------------
// K0: x, Wp, Wo  fp32 -> bf16 T32 panels, one launch.
// ---------------------------------------------------------------------------
__global__ __launch_bounds__(256) void k0_all(
    const float* __restrict__ x,  unsigned short* __restrict__ xbT,
    const float* __restrict__ Wp, unsigned short* __restrict__ WptT,
    const float* __restrict__ Wo, unsigned short* __restrict__ WotT)
{
    __shared__ float tile[32][33];
    const int bid = blockIdx.x;
    const float* in; unsigned short* outp; int C, c0, r0; size_t pbase; int psz;
    if (bid < 2048) {            // x[8][256][1024]: k=channel(256), n=s(1024)
        int rr = bid;
        int b = rr >> 8;
        in = x + (size_t)b * 256 * 1024;
        C = 1024; c0 = (rr & 31) * 32; r0 = ((rr >> 5) & 7) * 32;
        psz = 8192; pbase = (size_t)(b * 32 + (c0 >> 5)); outp = xbT;
    } else if (bid < 3584) {     // Wp[256][6144]: k=256, n=6144
        int rr = bid - 2048;
        in = Wp; C = 6144; c0 = (rr % 192) * 32; r0 = (rr / 192) * 32;
        psz = 8192; pbase = (size_t)(c0 >> 5); outp = WptT;
    } else {                     // Wo[2048][256]: k=2048, n=256
        int rr = bid - 3584;
        in = Wo; C = 256; c0 = (rr & 7) * 32; r0 = (rr >> 3) * 32;
        psz = 65536; pbase = (size_t)(c0 >> 5); outp = WotT;
    }
    const int tx = threadIdx.x & 31, ty = threadIdx.x >> 5;
#pragma unroll
    for (int j = 0; j < 4; j++)
        tile[ty + j * 8][tx] = in[(size_t)(r0 + ty + j * 8) * C + c0 + tx];
    __syncthreads();
    const int k = r0 + tx;                     // per-lane k index
    unsigned short* dst = outp + pbase * psz + ((k >> 3) * 32) * 8 + (k & 7);
#pragma unroll
    for (int j = 0; j < 4; j++)               // n%32 = ty + j*8
        dst[(ty + j * 8) * 8] = f2bf(tile[tx][ty + j * 8]);
}

// ---------------------------------------------------------------------------
// K1: qkv = xt @ Wp + bp.  32x32x16 MFMA, T32 in/out, conflict-free, dbuf.
// q/k blocks: A=Wpt (m=qkv dims), B=xb (n=tokens)  -> coalesced T32 epilogue.
// v blocks:   A=xb  (m=tokens),  B=Wpt (n=v dims)  -> coalesced permuted-v.
// ---------------------------------------------------------------------------
__global__ __launch_bounds__(256) void k1_qkv(
    const unsigned short* __restrict__ xbT, const unsigned short* __restrict__ WptT,
    const float* __restrict__ bp,
    unsigned short* __restrict__ qb, unsigned short* __restrict__ kb,
    unsigned short* __restrict__ vb)
{
    __shared__ unsigned short Xs[2][4096];   // 4 token panels x (4 chunks x 32 cells)
    __shared__ unsigned short Ws[2][4096];   // 4 dim panels
    const int t = threadIdx.x;
    const int wave = t >> 6, lane = t & 63;
    const int l32 = lane & 31, hw = lane >> 5;
    const int n0 = blockIdx.x * 128, m0 = blockIdx.y * 128;
    const int b = m0 >> 10, s0 = m0 & 1023;

    const int h = n0 / 768;
    const int rem = n0 - h * 768;
    const int tt = rem >> 8;                  // 0=q 1=k 2=v (block-uniform)
    const int dcol0 = rem & 255;

    const unsigned short* Xg = xbT + (size_t)(b * 32 + (s0 >> 5)) * TSH;
    const unsigned short* Wg = WptT + (size_t)(n0 >> 5) * TSH;

    f32x16 acc[4];
#pragma unroll
    for (int j = 0; j < 4; j++)
#pragma unroll
        for (int r = 0; r < 16; r++) acc[j][r] = 0.f;

    auto stage = [&](int buf, int kt) {
#pragma unroll
        for (int j = 0; j < 4; j++) {
            int rgn = wave * 4 + j;           // 16 regions of 1 KB
            if (rgn < 8) {
                int p = rgn >> 1, half = rgn & 1;
                load_lds16(Xg + (size_t)p * TSH + kt * 1024 + half * 512 + lane * 8,
                           &Xs[buf][p * 1024 + half * 512]);
            } else {
                int r2 = rgn - 8, p = r2 >> 1, half = r2 & 1;
                load_lds16(Wg + (size_t)p * TSH + kt * 1024 + half * 512 + lane * 8,
                           &Ws[buf][p * 1024 + half * 512]);
            }
        }
    };

    stage(0, 0);
    __syncthreads();

    for (int kt = 0; kt < 8; kt++) {
        const int cur = kt & 1;
        if (kt < 7) stage(cur ^ 1, kt + 1);
        const unsigned short* Fa = (tt < 2) ? &Ws[cur][wave * 1024] : &Xs[cur][wave * 1024];
        const unsigned short* Fb = (tt < 2) ? &Xs[cur][0] : &Ws[cur][0];
#pragma unroll
        for (int t2 = 0; t2 < 2; t2++) {
            frag8 af = *(const frag8*)(Fa + (2 * t2 + hw) * 256 + l32 * 8);
#pragma unroll
            for (int j = 0; j < 4; j++) {
                frag8 bf = *(const frag8*)(Fb + j * 1024 + (2 * t2 + hw) * 256 + l32 * 8);
                acc[j] = __builtin_amdgcn_mfma_f32_32x32x16_bf16(af, bf, acc[j], 0, 0, 0);
            }
        }
        __syncthreads();
    }

    if (tt < 2) {
        // D: col l32 = token (panel j), reg r -> d-local = 4hw + (r&3) + 8*(r>>2)
        const float sc = (tt == 0) ? QSCALE : 1.0f;
        unsigned short* dst0 = (tt == 0 ? qb : kb);
        const int dc0 = (dcol0 + wave * 32) >> 3;     // base dchunk
#pragma unroll
        for (int G = 0; G < 4; G++) {
            float4 bb = *(const float4*)(&bp[n0 + wave * 32 + 4 * hw + 8 * G]);
#pragma unroll
            for (int j = 0; j < 4; j++) {
                unsigned short* cell = dst0
                    + (size_t)((b * NH + h) * 32 + (s0 >> 5) + j) * TSH
                    + ((dc0 + G) * 32 + l32) * 8 + 4 * hw;
                uint2 st;
                st.x = pk2bf((acc[j][4 * G + 0] + bb.x) * sc, (acc[j][4 * G + 1] + bb.y) * sc);
                st.y = pk2bf((acc[j][4 * G + 2] + bb.z) * sc, (acc[j][4 * G + 3] + bb.w) * sc);
                *(uint2*)cell = st;
            }
        }
    } else {
        // D: col l32 = v-dim (panel j), reg r -> key-local = 4hw + (r&3) + 8*(r>>2)
        unsigned short* vt = vb + (size_t)((b * NH + h) * 32 + (s0 >> 5) + wave) * TSH;
#pragma unroll
        for (int j = 0; j < 4; j++) {
            const int d = dcol0 + j * 32 + l32;
            const float bv = bp[n0 + j * 32 + l32];
#pragma unroll
            for (int G = 0; G < 4; G++) {
                int g = G >> 1;
                unsigned short* cell = vt + (g * 2 + hw) * 2048 + d * 8 + 4 * (G & 1);
                uint2 st;
                st.x = pk2bf(acc[j][4 * G + 0] + bv, acc[j][4 * G + 1] + bv);
                st.y = pk2bf(acc[j][4 * G + 2] + bv, acc[j][4 * G + 3] + bv);
                *(uint2*)cell = st;
            }
        }
    }
}

// ---------------------------------------------------------------------------
// K2: attention (structure unchanged from r7/r8). Changes: PV operands
// swapped (A=vf, B=pf) so D col = q-row -> no shfl for 1/l and a coalesced
// uint2 T32 O-epilogue (O over qb, block-private panels; k3 stages from it).
// ---------------------------------------------------------------------------
__global__ __launch_bounds__(256, 2) void k2_attn(
    const unsigned short* __restrict__ qb, const unsigned short* __restrict__ kb,
    const unsigned short* __restrict__ vb, unsigned short* __restrict__ ob)
{
    __shared__ unsigned short Ks[2][TSH];
    __shared__ unsigned short Vs[2][TSH];

    const int t = threadIdx.x;
    const int wave = t >> 6, lane = t & 63;
    const int l32 = lane & 31, hw = lane >> 5;

    const int flat = blockIdx.x;
    const int xcd = flat & 7, tt2 = flat >> 3;
    const int qt = tt2 & 7;
    const int bh = xcd * 8 + (tt2 >> 3);

    frag8 qf[16];
    {
        const unsigned short* qp = qb + ((size_t)bh * 32 + qt * 4 + wave) * TSH
                                 + hw * 256 + l32 * 8;
#pragma unroll
        for (int s = 0; s < 16; s++) qf[s] = *(const frag8*)(qp + s * 512);
    }

    f32x16 acc[8];
#pragma unroll
    for (int nb = 0; nb < 8; nb++)
#pragma unroll
        for (int r = 0; r < 16; r++) acc[nb][r] = 0.f;
    float lsum = 0.f;

    const unsigned short* kt0 = kb + (size_t)bh * 32 * TSH;
    const unsigned short* vt0 = vb + (size_t)bh * 32 * TSH;

#pragma unroll
    for (int j = 0; j < 4; j++) {
        int c = wave * 4 + j;
        load_lds16(kt0 + c * 512 + lane * 8, &Ks[0][c * 512]);
        load_lds16(vt0 + c * 512 + lane * 8, &Vs[0][c * 512]);
    }
    __syncthreads();

    for (int kt = 0; kt < 32; kt++) {
        const int cur = kt & 1;

        if (kt < 31) {
            const unsigned short* kg = kt0 + (size_t)(kt + 1) * TSH;
            const unsigned short* vg = vt0 + (size_t)(kt + 1) * TSH;
#pragma unroll
            for (int j = 0; j < 4; j++) {
                int c = wave * 4 + j;
                load_lds16(kg + c * 512 + lane * 8, &Ks[cur ^ 1][c * 512]);
                load_lds16(vg + c * 512 + lane * 8, &Vs[cur ^ 1][c * 512]);
            }
        }

        f32x16 sa0, sa1;
#pragma unroll
        for (int r = 0; r < 16; r++) { sa0[r] = 0.f; sa1[r] = 0.f; }
#pragma unroll
        for (int s = 0; s < 16; s += 2) {
            frag8 kf0 = *(const frag8*)(&Ks[cur][(2 * s + hw) * 256 + l32 * 8]);
            frag8 kf1 = *(const frag8*)(&Ks[cur][(2 * s + 2 + hw) * 256 + l32 * 8]);
            sa0 = __builtin_amdgcn_mfma_f32_32x32x16_bf16(kf0, qf[s], sa0, 0, 0, 0);
            sa1 = __builtin_amdgcn_mfma_f32_32x32x16_bf16(kf1, qf[s + 1], sa1, 0, 0, 0);
        }

        float p[16];
#pragma unroll
        for (int e = 0; e < 16; e++) {
            p[e] = exp2f(sa0[e] + sa1[e]);
            lsum += p[e];
        }
        frag8 pf[2];
#pragma unroll
        for (int g = 0; g < 2; g++) {
            uint4 w;
            w.x = pk2bf(p[g * 8 + 0], p[g * 8 + 1]);
            w.y = pk2bf(p[g * 8 + 2], p[g * 8 + 3]);
            w.z = pk2bf(p[g * 8 + 4], p[g * 8 + 5]);
            w.w = pk2bf(p[g * 8 + 6], p[g * 8 + 7]);
            pf[g] = *(frag8*)&w;
        }

        // PV with A=vf, B=pf: D[m=dcol][n=qrow] = (P·V)^T cellwise = O
#pragma unroll
        for (int g = 0; g < 2; g++)
#pragma unroll
            for (int nb = 0; nb < 8; nb++) {
                frag8 vf = *(const frag8*)(&Vs[cur][(g * 2 + hw) * 2048 + (nb * 32 + l32) * 8]);
                acc[nb] = __builtin_amdgcn_mfma_f32_32x32x16_bf16(vf, pf[g], acc[nb], 0, 0, 0);
            }

        __syncthreads();
    }

    lsum += __shfl_xor(lsum, 32);
    const float li = 1.f / lsum;    // col l32 = q-row = this lane's row

    // O epilogue: T32 per-bh (q/k format), own panel (alias-safe over qb)
    unsigned short* opan = ob + ((size_t)bh * 32 + qt * 4 + wave) * TSH;
#pragma unroll
    for (int nb = 0; nb < 8; nb++)
#pragma unroll
        for (int G = 0; G < 4; G++) {
            unsigned short* cell = opan + ((nb * 4 + G) * 32 + l32) * 8 + 4 * hw;
            uint2 st;
            st.x = pk2bf(acc[nb][4 * G + 0] * li, acc[nb][4 * G + 1] * li);
            st.y = pk2bf(acc[nb][4 * G + 2] * li, acc[nb][4 * G + 3] * li);
            *(uint2*)cell = st;
        }
}

// ---------------------------------------------------------------------------
// K3: out = O @ Wo + bo + xt, 32x32x16 MFMA, transposed (m=ch, n=tokens),
// 64x128 tiles (256 blocks), BK=32, dbuf, conflict-free T32 reads.
// O read from qb in per-bh T32 (k2's output format).
// ---------------------------------------------------------------------------
__global__ __launch_bounds__(256) void k3_proj(
    const unsigned short* __restrict__ Ob, const unsigned short* __restrict__ WotT,
    const float* __restrict__ bo, const float* __restrict__ x,
    float* __restrict__ out)
{
    __shared__ unsigned short As[2][2048];   // 2 ch panels x 4 chunks x 32 cells
    __shared__ unsigned short Bs[2][4096];   // 4 token panels
    const int t = threadIdx.x;
    const int wave = t >> 6, lane = t & 63;
    const int l32 = lane & 31, hw = lane >> 5;
    const int wc = wave & 1, wt = wave >> 1;
    const int c0 = blockIdx.x * 64, m0 = blockIdx.y * 128;
    const int b = m0 >> 10, s0 = m0 & 1023;

    const unsigned short* Ag = WotT + (size_t)(c0 >> 5) * 65536;

    f32x16 acc[2];
#pragma unroll
    for (int pp = 0; pp < 2; pp++)
#pragma unroll
        for (int r = 0; r < 16; r++) acc[pp][r] = 0.f;

    auto stage = [&](int buf, int kt) {
        const int hh = kt >> 3, lc = (kt & 7) * 4;    // head, local chunk base
#pragma unroll
        for (int j = 0; j < 3; j++) {
            int rgn = wave * 3 + j;                    // 12 regions of 1 KB
            if (rgn < 4) {
                int wp = rgn >> 1, half = rgn & 1;
                load_lds16(Ag + (size_t)wp * 65536 + kt * 1024 + half * 512 + lane * 8,
                           &As[buf][wp * 1024 + half * 512]);
            } else {
                int r2 = rgn - 4, p = r2 >> 1, half = r2 & 1;
                load_lds16(Ob + (size_t)((b * NH + hh) * 32 + (s0 >> 5) + p) * TSH
                               + lc * 256 + half * 512 + lane * 8,
                           &Bs[buf][p * 1024 + half * 512]);
            }
        }
    };

    stage(0, 0);
    __syncthreads();

    for (int kt = 0; kt < 64; kt++) {
        const int cur = kt & 1;
        if (kt < 63) stage(cur ^ 1, kt + 1);
#pragma unroll
        for (int t2 = 0; t2 < 2; t2++) {
            frag8 af = *(const frag8*)(&As[cur][wc * 1024 + (2 * t2 + hw) * 256 + l32 * 8]);
#pragma unroll
            for (int pp = 0; pp < 2; pp++) {
                frag8 bf = *(const frag8*)(&Bs[cur][(wt * 2 + pp) * 1024 + (2 * t2 + hw) * 256 + l32 * 8]);
                acc[pp] = __builtin_amdgcn_mfma_f32_32x32x16_bf16(af, bf, acc[pp], 0, 0, 0);
            }
        }
        __syncthreads();
    }

    // D: col l32 = token (panel wt*2+pp), reg r -> ch-local = 4hw+(r&3)+8*(r>>2)
#pragma unroll
    for (int G = 0; G < 4; G++) {
        float4 bb = *(const float4*)(&bo[c0 + wc * 32 + 4 * hw + 8 * G]);
#pragma unroll
        for (int pp = 0; pp < 2; pp++) {
            const int s = s0 + wt * 64 + pp * 32 + l32;
#pragma unroll
            for (int e = 0; e < 4; e++) {
                const int ch = c0 + wc * 32 + 4 * hw + 8 * G + e;
                const float bbe = (e == 0) ? bb.x : (e == 1) ? bb.y : (e == 2) ? bb.z : bb.w;
                size_t off = (size_t)(b * 256 + ch) * 1024 + s;
                out[off] = acc[pp][4 * G + e] + bbe + x[off];
            }
        }
    }
}

// ---------------------------------------------------------------------------
extern "C" void kernel_launch(void* const* d_in, const int* in_sizes, int n_in,
                              void* d_out, int out_size, void* d_ws, size_t ws_size,
                              hipStream_t stream)
{
    const float* x  = (const float*)d_in[0];
    const float* Wp = (const float*)d_in[1];
    const float* bp = (const float*)d_in[2];
    const float* Wo = (const float*)d_in[3];
    const float* bo = (const float*)d_in[4];
    float* out = (float*)d_out;

    char* ws = (char*)d_ws;
    unsigned short* qb   = (unsigned short*)(ws);                // T32; O overwrites (same panels)
    unsigned short* kb   = (unsigned short*)(ws + 33554432);     // T32
    unsigned short* vb   = (unsigned short*)(ws + 67108864);     // key-permuted tiles
    unsigned short* xbT  = (unsigned short*)(ws + 100663296);    // T32 [b*32+sblk] panels
    unsigned short* WptT = (unsigned short*)(ws + 104857600);    // T32 192 panels
    unsigned short* WotT = (unsigned short*)(ws + 108003328);    // T32 8 panels (K=2048)

    k0_all<<<dim3(4096), 256, 0, stream>>>(x, xbT, Wp, WptT, Wo, WotT);
    k1_qkv<<<dim3(48, 64), 256, 0, stream>>>(xbT, WptT, bp, qb, kb, vb);
    k2_attn<<<dim3(512), 256, 0, stream>>>(qb, kb, vb, qb /* O over Q */);
    k3_proj<<<dim3(4, 64), 256, 0, stream>>>(qb, WotT, bo, x, out);
}